// Round 16
// baseline (393.103 us; speedup 1.0000x reference)
//
#include <hip/hip_runtime.h>
#include <math.h>

typedef short  short8 __attribute__((ext_vector_type(8)));
typedef float  f32x4  __attribute__((ext_vector_type(4)));

#define ZQ_ELEMS 4194304    // 16*64*64*64
#define KC       1024
#define EPS_HALF 0.005f
#define PXB      128

// Output layout (fp32, concat): [0,4194304) z_q_st ; [4194304] vq_loss ;
// [4194305, 4259841) indices (as float)
//
// ws layout (bytes):
//   [0,262144)           ushort epack[1024][128]   per code: hi[64] | lo[64]
//   [262144,266240)      float  enorm[1024]
//   [266240,266244)      int    risky_cnt
//   [266752,268800)      int    done[512]
//   [270336,524288)      int    risky[63488]
//   [524288,2621440)     double pbest[4][65536]
//   [2621440,3670016)    float  pb2[4][65536]

__device__ inline unsigned short bf16_rne(float f) {
    union { float fv; unsigned u; } a; a.fv = f;
    unsigned r = a.u + 0x7FFFu + ((a.u >> 16) & 1u);
    return (unsigned short)(r >> 16);
}
__device__ inline float bf16_to_f(unsigned short h) {
    union { unsigned u; float fv; } a; a.u = ((unsigned)h) << 16;
    return a.fv;
}
// packed (score, 1023-code) ordered compare via f64 max; near-ties are all
// rescored exactly, so tie direction here is irrelevant.
__device__ inline double dpack(float hi, unsigned lo) {
    return __hiloint2double(__float_as_int(hi), (int)lo);
}
__device__ inline float dhi(double d) { return __int_as_float(__double2hiint(d)); }
__device__ inline unsigned dlo(double d) { return (unsigned)__double2loint(d); }

__global__ __launch_bounds__(256) void vq_prep(const float* __restrict__ emb,
        unsigned short* __restrict__ epack, float* __restrict__ enorm,
        int* __restrict__ risky_cnt, int* __restrict__ done,
        float* __restrict__ out) {
    const int k = blockIdx.x * 256 + threadIdx.x;   // grid 4
    if (k == 0) { *risky_cnt = 0; out[ZQ_ELEMS] = 0.f; }
    if (k < 512) done[k] = 0;
    const float4* e4 = (const float4*)(emb + k * 64);
    float s = 0.f;
#pragma unroll
    for (int j = 0; j < 16; ++j) {
        float4 v = e4[j];
        float vv[4] = {v.x, v.y, v.z, v.w};
        ushort4 hv, lv;
        unsigned short h[4], l[4];
#pragma unroll
        for (int t = 0; t < 4; ++t) {
            s = fmaf(vv[t], vv[t], s);
            h[t] = bf16_rne(vv[t]);
            l[t] = bf16_rne(vv[t] - bf16_to_f(h[t]));
        }
        hv.x = h[0]; hv.y = h[1]; hv.z = h[2]; hv.w = h[3];
        lv.x = l[0]; lv.y = l[1]; lv.z = l[2]; lv.w = l[3];
        *(ushort4*)(epack + k * 128 + j * 4)      = hv;
        *(ushort4*)(epack + k * 128 + 64 + j * 4) = lv;
    }
    enorm[k] = s;
}

// Scan (r10 body) + last-block-fused final. Block = 128 px x 256 codes.
// Grid 2048 = 512 px-blocks x 4 code-groups. The 4th-arriving block of each
// px-group merges partials, writes indices, compacts risky, gathers z_q + loss.
__global__ __launch_bounds__(256, 2) void vq_scan(const float* __restrict__ z_e,
        const unsigned short* __restrict__ epack, const float* __restrict__ enorm,
        const float* __restrict__ emb,
        double* __restrict__ pbest, float* __restrict__ pb2,
        float* __restrict__ out, int* __restrict__ risky_cnt,
        int* __restrict__ risky, int* __restrict__ done) {
    const int tid  = threadIdx.x;
    const int lane = tid & 63;
    const int col  = lane & 15;
    const int g    = lane >> 4;
    const int wv   = __builtin_amdgcn_readfirstlane(tid >> 6);
    const int pxblock = blockIdx.x >> 2;
    const int grp     = blockIdx.x & 3;
    const int cbase   = grp * 256 + wv * 64;   // this wave's 64 codes
    const int pblk    = pxblock * PXB;

    __shared__ __align__(16) char smem[38912];
    unsigned short* afrag = (unsigned short*)smem;        // [128 px][hi64|lo64]
    double* mrgB = (double*)(smem + 32768);               // [4][128]
    float*  mrgS = (float*)(smem + 36864);                // [4][128]
    __shared__ int s_last;
    __shared__ float sred[4];

    // ---- stage + convert 128 pixels into LDS (once per block)
    {
        const int lp   = tid & 127;
        const int half = tid >> 7;                 // dims half*32 .. +32
        const int pg   = pblk + lp;
        const float* zb = z_e + (pg >> 12) * 262144 + (pg & 4095);
        const int sx = (lp & 7) << 3;
#pragma unroll
        for (int s8 = 0; s8 < 4; ++s8) {
            const int d0 = half * 32 + s8 * 8;
            short8 H, L;
#pragma unroll
            for (int j = 0; j < 8; ++j) {
                float v = zb[(d0 + j) * 4096];
                unsigned short h = bf16_rne(v);
                H[j] = (short)h;
                L[j] = (short)bf16_rne(v - bf16_to_f(h));
            }
            const int sw = d0 ^ sx;                // 16B-granular XOR swizzle
            *(short8*)&afrag[lp * 128 + sw]      = H;
            *(short8*)&afrag[lp * 128 + 64 + sw] = L;
        }
    }

    // ---- A fragments (codes) - loaded once, resident
    short8 ah[4][2], al[4][2];
    f32x4 enf[4];
    int clo[4][4];
    const int K1 = 1023 - cbase - g * 4;
#pragma unroll
    for (int t = 0; t < 4; ++t) {
        const int code = cbase + t * 16 + col;
        const short8* ph = (const short8*)(epack + code * 128) + g;
        ah[t][0] = ph[0]; ah[t][1] = ph[4];
        al[t][0] = ph[8]; al[t][1] = ph[12];
        const float4 e4 = *(const float4*)(enorm + cbase + t * 16 + g * 4);
        enf[t][0] = -0.5f * e4.x; enf[t][1] = -0.5f * e4.y;
        enf[t][2] = -0.5f * e4.z; enf[t][3] = -0.5f * e4.w;
#pragma unroll
        for (int r = 0; r < 4; ++r) clo[t][r] = K1 - t * 16 - r;
    }
    __syncthreads();

    const f32x4 zero4 = {0.f, 0.f, 0.f, 0.f};
    const int g8 = g * 8;

    // ---- sweep pixels: 8 iters x 16 px; all operands reg/LDS-resident
#pragma unroll 2
    for (int it = 0; it < PXB / 16; ++it) {
        const int lpx = it * 16 + col;             // this lane's pixel (local)
        const int sxp = (lpx & 7) << 3;
        const unsigned short* ap = &afrag[lpx * 128];
        const short8 bh0 = *(const short8*)&ap[(g8        ) ^ sxp];
        const short8 bh1 = *(const short8*)&ap[(32 + g8   ) ^ sxp];
        const short8 bl0 = *(const short8*)&ap[64 + ((g8     ) ^ sxp)];
        const short8 bl1 = *(const short8*)&ap[64 + ((32 + g8) ^ sxp)];

        double B = dpack(-INFINITY, 0u);
        float  S = -INFINITY;
#pragma unroll
        for (int t = 0; t < 4; ++t) {
            f32x4 aA, aB;   // chunk0 / chunk1 independent 3-chains
            aA = __builtin_amdgcn_mfma_f32_16x16x32_bf16(ah[t][0], bh0, enf[t], 0, 0, 0);
            aB = __builtin_amdgcn_mfma_f32_16x16x32_bf16(ah[t][1], bh1, zero4, 0, 0, 0);
            aA = __builtin_amdgcn_mfma_f32_16x16x32_bf16(al[t][0], bh0, aA, 0, 0, 0);
            aB = __builtin_amdgcn_mfma_f32_16x16x32_bf16(al[t][1], bh1, aB, 0, 0, 0);
            aA = __builtin_amdgcn_mfma_f32_16x16x32_bf16(ah[t][0], bl0, aA, 0, 0, 0);
            aB = __builtin_amdgcn_mfma_f32_16x16x32_bf16(ah[t][1], bl1, aB, 0, 0, 0);
#pragma unroll
            for (int r = 0; r < 4; ++r) {
                const float v = aA[r] + aB[r];     // score(code = cbase+t*16+g*4+r, px)
                S = __builtin_amdgcn_fmed3f(dhi(B), S, v);
                B = fmax(B, dpack(v, (unsigned)clo[t][r]));
            }
        }
        // reduce over g (lane bits 4-5): each lane ends with its pixel's result
#pragma unroll
        for (int s = 16; s < 64; s <<= 1) {
            const double ob = __shfl_xor(B, s, 64);
            const float  o2 = __shfl_xor(S, s, 64);
            S = __builtin_amdgcn_fmed3f(dhi(B), dhi(ob), fmaxf(S, o2));
            B = fmax(B, ob);
        }
        if (g == 0) { mrgB[wv * PXB + lpx] = B; mrgS[wv * PXB + lpx] = S; }
    }

    // ---- merge the 4 waves' 64-code results -> per-(px, 256-code group) partial
    __syncthreads();
    if (tid < PXB) {
        double B = mrgB[tid];
        float  S = mrgS[tid];
#pragma unroll
        for (int w = 1; w < 4; ++w) {
            const double ob = mrgB[w * PXB + tid];
            const float  o2 = mrgS[w * PXB + tid];
            S = __builtin_amdgcn_fmed3f(dhi(B), dhi(ob), fmaxf(S, o2));
            B = fmax(B, ob);
        }
        const int pxg = pblk + tid;
        pbest[grp * 65536 + pxg] = B;
        pb2[grp * 65536 + pxg]   = S;
    }

    // ---- last-arriving block of this px-group runs the final phase
    __threadfence();
    __syncthreads();
    if (tid == 0) s_last = (atomicAdd(&done[pxblock], 1) == 3);
    __syncthreads();
    if (!s_last) return;
    __threadfence();

    float (*zqt)[132] = (float (*)[132])smem;     // [64 d][128 px +4 pad] = 33792 B
    int* sidx = (int*)(smem + 33792);             // [128]

    // merge 4 code-group partials (volatile: other blocks wrote them)
    if (tid < PXB) {
        const volatile double* vB = pbest;
        const volatile float*  vS = pb2;
        const int px = pblk + tid;
        double B = vB[px];
        float  S = vS[px];
#pragma unroll
        for (int gq = 1; gq < 4; ++gq) {
            const double ob = vB[gq * 65536 + px];
            const float  o2 = vS[gq * 65536 + px];
            S = __builtin_amdgcn_fmed3f(dhi(B), dhi(ob), fmaxf(S, o2));
            B = fmax(B, ob);
        }
        const int idx = 1023 - (int)dlo(B);
        sidx[tid] = idx;
        out[ZQ_ELEMS + 1 + px] = (float)idx;
        const bool risk = (dhi(B) - S < EPS_HALF);
        const unsigned long long m = __ballot(risk);
        int base = 0;
        if (lane == 0 && m) base = atomicAdd(risky_cnt, __popcll(m));
        base = __shfl(base, 0, 64);
        if (risk) risky[base + __popcll(m & ((1ull << lane) - 1ull))] = px;
    }
    __syncthreads();

    // gather: coalesced codebook-row reads, d-major transposed store
#pragma unroll
    for (int i = 0; i < 32; ++i) {
        const int p = wv * 32 + i;
        const int k = sidx[p];                    // LDS, wave-uniform broadcast
        zqt[lane][p] = emb[k * 64 + lane];
    }
    __syncthreads();

    // (B,D,H,W)-major float4 writes + fused loss
    const int batch = pblk >> 12;
    const int hw0   = pblk & 4095;
    const int p4 = (tid & 31) * 4;                // 0..124
    const int db = tid >> 5;                      // 0..7
    const float* zeb = z_e + batch * 262144 + hw0;
    float* ob = out + batch * 262144 + hw0;
    float ss = 0.f;
#pragma unroll
    for (int h = 0; h < 8; ++h) {
        const int d = db + h * 8;
        const float4 q = *(const float4*)&zqt[d][p4];
        const float4 z = *(const float4*)(zeb + d * 4096 + p4);
        *(float4*)(ob + d * 4096 + p4) = q;
        const float e0 = q.x - z.x, e1 = q.y - z.y, e2 = q.z - z.z, e3 = q.w - z.w;
        ss += e0 * e0 + e1 * e1 + e2 * e2 + e3 * e3;
    }
    for (int off = 32; off; off >>= 1) ss += __shfl_down(ss, off, 64);
    if (lane == 0) sred[wv] = ss;
    __syncthreads();
    if (tid == 0)
        atomicAdd(out + ZQ_ELEMS,
                  ((sred[0] + sred[1]) + (sred[2] + sred[3])) * (1.25f / (float)ZQ_ELEMS));
}

// Exact fp64 fixup: wave per flagged pixel; emb staged per 64-code tile into
// padded LDS. Patches idx + z_q row + loss delta. Grid 512; idle blocks exit.
__global__ __launch_bounds__(256) void vq_fix(const float* __restrict__ z_e,
        const float* __restrict__ emb, float* __restrict__ out,
        const int* __restrict__ cnt, const int* __restrict__ list) {
    const int n = *cnt;
    if ((int)blockIdx.x * 4 >= n) return;
    __shared__ float etile[64][65];
    const int tid  = threadIdx.x;
    const int lane = tid & 63;
    const int wv   = __builtin_amdgcn_readfirstlane(tid >> 6);

    for (int base = blockIdx.x * 4; base < n; base += gridDim.x * 4) {
        const int item = base + wv;
        const bool active = item < n;
        int pix = 0, oldk = 0;
        float f[64];
        if (active) {
            pix = list[item];
            const float* zb = z_e + (pix >> 12) * 262144 + (pix & 4095);
#pragma unroll
            for (int d = 0; d < 64; ++d) f[d] = zb[d * 4096];
            oldk = (int)out[ZQ_ELEMS + 1 + pix];
        }
        double best = INFINITY; int bk = KC;
        double dold = 0.0;
        for (int j = 0; j < 16; ++j) {
            __syncthreads();
#pragma unroll
            for (int i = 0; i < 16; ++i) {
                const int idx = i * 256 + tid;
                etile[idx >> 6][idx & 63] = emb[j * 4096 + idx];
            }
            __syncthreads();
            if (active) {
                const int k = j * 64 + lane;
                double a0 = 0.0, a1 = 0.0;
#pragma unroll
                for (int d = 0; d < 64; d += 2) {
                    const double d0 = (double)f[d]     - (double)etile[lane][d];
                    const double d1 = (double)f[d + 1] - (double)etile[lane][d + 1];
                    a0 = fma(d0, d0, a0);
                    a1 = fma(d1, d1, a1);
                }
                const double acc = a0 + a1;
                if (acc < best || (acc == best && k < bk)) { best = acc; bk = k; }
                if (k == oldk) dold = acc;
            }
        }
        if (active) {
            for (int off = 32; off; off >>= 1) {
                const double ov = __shfl_down(best, off, 64);
                const int    oi = __shfl_down(bk, off, 64);
                if (ov < best || (ov == best && oi < bk)) { best = ov; bk = oi; }
            }
            for (int off = 32; off; off >>= 1) dold += __shfl_down(dold, off, 64);
            bk   = __shfl(bk, 0, 64);
            best = __shfl(best, 0, 64);
            dold = __shfl(dold, 0, 64);
            if (bk != oldk) {
                if (lane == 0) out[ZQ_ELEMS + 1 + pix] = (float)bk;
                out[(pix >> 12) * 262144 + (pix & 4095) + lane * 4096] = emb[bk * 64 + lane];
                if (lane == 0)
                    atomicAdd(out + ZQ_ELEMS,
                              (float)((best - dold) * (1.25 / (double)ZQ_ELEMS)));
            }
        }
    }
}

extern "C" void kernel_launch(void* const* d_in, const int* in_sizes, int n_in,
                              void* d_out, int out_size, void* d_ws, size_t ws_size,
                              hipStream_t stream) {
    const float* z_e = (const float*)d_in[0];
    const float* emb = (const float*)d_in[1];
    float* out = (float*)d_out;
    char* ws = (char*)d_ws;
    unsigned short* epack = (unsigned short*)ws;
    float*  enorm     = (float*)(ws + 262144);
    int*    risky_cnt = (int*)(ws + 266240);
    int*    done      = (int*)(ws + 266752);
    int*    risky     = (int*)(ws + 270336);
    double* pbest     = (double*)(ws + 524288);     // 2 MB
    float*  pb2       = (float*)(ws + 2621440);     // 1 MB

    vq_prep<<<4, 256, 0, stream>>>(emb, epack, enorm, risky_cnt, done, out);
    vq_scan<<<2048, 256, 0, stream>>>(z_e, epack, enorm, emb, pbest, pb2,
                                      out, risky_cnt, risky, done);
    vq_fix<<<512, 256, 0, stream>>>(z_e, emb, out, risky_cnt, risky);
}

// Round 17
// 90.033 us; speedup vs baseline: 4.3662x; 4.3662x over previous
//
#include <hip/hip_runtime.h>
#include <math.h>

typedef short  short8 __attribute__((ext_vector_type(8)));
typedef float  f32x4  __attribute__((ext_vector_type(4)));

#define ZQ_ELEMS 4194304    // 16*64*64*64
#define KC       1024
#define EPS_HALF 0.005f
#define PXB      128

// Output layout (fp32, concat): [0,4194304) z_q_st ; [4194304] vq_loss ;
// [4194305, 4259841) indices (as float)
//
// ws layout (bytes):
//   [0,262144)           ushort epack[1024][128]   per code: hi[64] | lo[64]
//   [262144,266240)      float  enorm[1024]
//   [266240,266244)      int    risky_cnt
//   [270336,524288)      int    risky[63488]
//   [524288,2621440)     double pbest[4][65536]
//   [2621440,3670016)    float  pb2[4][65536]

__device__ inline unsigned short bf16_rne(float f) {
    union { float fv; unsigned u; } a; a.fv = f;
    unsigned r = a.u + 0x7FFFu + ((a.u >> 16) & 1u);
    return (unsigned short)(r >> 16);
}
__device__ inline float bf16_to_f(unsigned short h) {
    union { unsigned u; float fv; } a; a.u = ((unsigned)h) << 16;
    return a.fv;
}
// packed (score, 1023-code) ordered compare via f64 max; near-ties are all
// rescored exactly, so tie direction here is irrelevant.
__device__ inline double dpack(float hi, unsigned lo) {
    return __hiloint2double(__float_as_int(hi), (int)lo);
}
__device__ inline float dhi(double d) { return __int_as_float(__double2hiint(d)); }
__device__ inline unsigned dlo(double d) { return (unsigned)__double2loint(d); }

__global__ __launch_bounds__(256) void vq_prep(const float* __restrict__ emb,
        unsigned short* __restrict__ epack, float* __restrict__ enorm,
        int* __restrict__ risky_cnt, float* __restrict__ out) {
    const int k = blockIdx.x * 256 + threadIdx.x;   // grid 4
    if (k == 0) { *risky_cnt = 0; out[ZQ_ELEMS] = 0.f; }
    const float4* e4 = (const float4*)(emb + k * 64);
    float s = 0.f;
#pragma unroll
    for (int j = 0; j < 16; ++j) {
        float4 v = e4[j];
        float vv[4] = {v.x, v.y, v.z, v.w};
        ushort4 hv, lv;
        unsigned short h[4], l[4];
#pragma unroll
        for (int t = 0; t < 4; ++t) {
            s = fmaf(vv[t], vv[t], s);
            h[t] = bf16_rne(vv[t]);
            l[t] = bf16_rne(vv[t] - bf16_to_f(h[t]));
        }
        hv.x = h[0]; hv.y = h[1]; hv.z = h[2]; hv.w = h[3];
        lv.x = l[0]; lv.y = l[1]; lv.z = l[2]; lv.w = l[3];
        *(ushort4*)(epack + k * 128 + j * 4)      = hv;
        *(ushort4*)(epack + k * 128 + 64 + j * 4) = lv;
    }
    enorm[k] = s;
}

// Scan: r10 geometry (block = 128 px x 256 codes, grid 2048 = 512 px-blocks x
// 4 code-groups) with DEFERRED cross-lane reduce: per-pixel running (best,2nd)
// stay in registers across the 8 pixel-iterations; all shfl reduces run after
// the loop (8 independent chains -> ILP hides bpermute latency). Merge buffers
// alias the then-dead afrag LDS (total 32 KB).
__global__ __launch_bounds__(256) void vq_scan(const float* __restrict__ z_e,
        const unsigned short* __restrict__ epack, const float* __restrict__ enorm,
        double* __restrict__ pbest, float* __restrict__ pb2) {
    const int tid  = threadIdx.x;
    const int lane = tid & 63;
    const int col  = lane & 15;
    const int g    = lane >> 4;
    const int wv   = __builtin_amdgcn_readfirstlane(tid >> 6);
    const int pxblock = blockIdx.x >> 2;
    const int grp     = blockIdx.x & 3;
    const int cbase   = grp * 256 + wv * 64;   // this wave's 64 codes
    const int pblk    = pxblock * PXB;

    __shared__ __align__(16) char smem[32768];
    unsigned short* afrag = (unsigned short*)smem;   // [128 px][hi64|lo64], swizzled
    double* mrgB = (double*)smem;                    // aliased after loop: [4][128]
    float*  mrgS = (float*)(smem + 4096);            // [4][128]

    // ---- stage + convert 128 pixels into LDS (once per block)
    {
        const int lp   = tid & 127;
        const int half = tid >> 7;                 // dims half*32 .. +32
        const int pg   = pblk + lp;
        const float* zb = z_e + (pg >> 12) * 262144 + (pg & 4095);
        const int sx = (lp & 7) << 3;
#pragma unroll
        for (int s8 = 0; s8 < 4; ++s8) {
            const int d0 = half * 32 + s8 * 8;
            short8 H, L;
#pragma unroll
            for (int j = 0; j < 8; ++j) {
                float v = zb[(d0 + j) * 4096];
                unsigned short h = bf16_rne(v);
                H[j] = (short)h;
                L[j] = (short)bf16_rne(v - bf16_to_f(h));
            }
            const int sw = d0 ^ sx;                // 16B-granular XOR swizzle
            *(short8*)&afrag[lp * 128 + sw]      = H;
            *(short8*)&afrag[lp * 128 + 64 + sw] = L;
        }
    }

    // ---- A fragments (codes) - loaded once, resident
    short8 ah[4][2], al[4][2];
    f32x4 enf[4];
    int clo[4][4];
    const int K1 = 1023 - cbase - g * 4;
#pragma unroll
    for (int t = 0; t < 4; ++t) {
        const int code = cbase + t * 16 + col;
        const short8* ph = (const short8*)(epack + code * 128) + g;
        ah[t][0] = ph[0]; ah[t][1] = ph[4];
        al[t][0] = ph[8]; al[t][1] = ph[12];
        const float4 e4 = *(const float4*)(enorm + cbase + t * 16 + g * 4);
        enf[t][0] = -0.5f * e4.x; enf[t][1] = -0.5f * e4.y;
        enf[t][2] = -0.5f * e4.z; enf[t][3] = -0.5f * e4.w;
#pragma unroll
        for (int r = 0; r < 4; ++r) clo[t][r] = K1 - t * 16 - r;
    }
    __syncthreads();

    const f32x4 zero4 = {0.f, 0.f, 0.f, 0.f};
    const int g8 = g * 8;

    double Brun[8];
    float  Srun[8];
#pragma unroll
    for (int it = 0; it < 8; ++it) { Brun[it] = dpack(-INFINITY, 0u); Srun[it] = -INFINITY; }

    // ---- sweep pixels: 8 iters x 16 px; NO cross-lane ops in the loop
#pragma unroll
    for (int it = 0; it < 8; ++it) {
        const int lpx = it * 16 + col;             // this lane's pixel (local)
        const int sxp = (lpx & 7) << 3;
        const unsigned short* ap = &afrag[lpx * 128];
        const short8 bh0 = *(const short8*)&ap[(g8        ) ^ sxp];
        const short8 bh1 = *(const short8*)&ap[(32 + g8   ) ^ sxp];
        const short8 bl0 = *(const short8*)&ap[64 + ((g8     ) ^ sxp)];
        const short8 bl1 = *(const short8*)&ap[64 + ((32 + g8) ^ sxp)];

        double B = Brun[it];
        float  S = Srun[it];
#pragma unroll
        for (int t = 0; t < 4; ++t) {
            f32x4 aA, aB;   // chunk0 / chunk1 independent 3-chains
            aA = __builtin_amdgcn_mfma_f32_16x16x32_bf16(ah[t][0], bh0, enf[t], 0, 0, 0);
            aB = __builtin_amdgcn_mfma_f32_16x16x32_bf16(ah[t][1], bh1, zero4, 0, 0, 0);
            aA = __builtin_amdgcn_mfma_f32_16x16x32_bf16(al[t][0], bh0, aA, 0, 0, 0);
            aB = __builtin_amdgcn_mfma_f32_16x16x32_bf16(al[t][1], bh1, aB, 0, 0, 0);
            aA = __builtin_amdgcn_mfma_f32_16x16x32_bf16(ah[t][0], bl0, aA, 0, 0, 0);
            aB = __builtin_amdgcn_mfma_f32_16x16x32_bf16(ah[t][1], bl1, aB, 0, 0, 0);
#pragma unroll
            for (int r = 0; r < 4; ++r) {
                const float v = aA[r] + aB[r];     // score(code = cbase+t*16+g*4+r, px)
                S = __builtin_amdgcn_fmed3f(dhi(B), S, v);
                B = fmax(B, dpack(v, (unsigned)clo[t][r]));
            }
        }
        Brun[it] = B;
        Srun[it] = S;
    }

    // ---- deferred reduces over g (lane bits 4-5): 8 independent shfl chains
#pragma unroll
    for (int it = 0; it < 8; ++it) {
        double B = Brun[it];
        float  S = Srun[it];
#pragma unroll
        for (int s = 16; s < 64; s <<= 1) {
            const double ob = __shfl_xor(B, s, 64);
            const float  o2 = __shfl_xor(S, s, 64);
            S = __builtin_amdgcn_fmed3f(dhi(B), dhi(ob), fmaxf(S, o2));
            B = fmax(B, ob);
        }
        Brun[it] = B;
        Srun[it] = S;
    }

    __syncthreads();          // all afrag reads complete -> safe to alias as mrg
    if (g == 0) {
#pragma unroll
        for (int it = 0; it < 8; ++it) {
            mrgB[wv * PXB + it * 16 + col] = Brun[it];
            mrgS[wv * PXB + it * 16 + col] = Srun[it];
        }
    }
    __syncthreads();

    // ---- merge the 4 waves' 64-code results -> per-(px, 256-code group) partial
    if (tid < PXB) {
        double B = mrgB[tid];
        float  S = mrgS[tid];
#pragma unroll
        for (int w = 1; w < 4; ++w) {
            const double ob = mrgB[w * PXB + tid];
            const float  o2 = mrgS[w * PXB + tid];
            S = __builtin_amdgcn_fmed3f(dhi(B), dhi(ob), fmaxf(S, o2));
            B = fmax(B, ob);
        }
        const int pxg = pblk + tid;
        pbest[grp * 65536 + pxg] = B;
        pb2[grp * 65536 + pxg]   = S;
    }
}

// Fused merge + flag-compact + transpose-gather + loss (NO inline rescore).
// Block = 64 px, 256 thr. Grid 1024. Uniform work -> no straggler tail.
__global__ __launch_bounds__(256) void vq_final(const float* __restrict__ z_e,
        const float* __restrict__ emb, const double* __restrict__ pbest,
        const float* __restrict__ pb2, float* __restrict__ out,
        int* __restrict__ risky_cnt, int* __restrict__ risky) {
    __shared__ float zq[64][65];       // +1 pad: conflict-free transpose
    __shared__ int   sidx[64];
    __shared__ float sred[4];
    const int tid  = threadIdx.x;
    const int lane = tid & 63;
    const int w    = __builtin_amdgcn_readfirstlane(tid >> 6);
    const int pblk = blockIdx.x * 64;
    const int batch = pblk >> 12;
    const int hw0   = pblk & 4095;

    // ---- step 1: wave 0 merges partials, writes provisional idx, compacts risky
    if (w == 0) {
        const int px = pblk + lane;
        double B = pbest[px];
        float  S = pb2[px];
#pragma unroll
        for (int gq = 1; gq < 4; ++gq) {
            const double ob = pbest[gq * 65536 + px];
            const float  o2 = pb2[gq * 65536 + px];
            S = __builtin_amdgcn_fmed3f(dhi(B), dhi(ob), fmaxf(S, o2));
            B = fmax(B, ob);
        }
        const int idx = 1023 - (int)dlo(B);
        sidx[lane] = idx;
        out[ZQ_ELEMS + 1 + px] = (float)idx;
        const bool risk = (dhi(B) - S < EPS_HALF);
        const unsigned long long m = __ballot(risk);
        int base = 0;
        if (lane == 0 && m) base = atomicAdd(risky_cnt, __popcll(m));
        base = __shfl(base, 0, 64);
        if (risk) risky[base + __popcll(m & ((1ull << lane) - 1ull))] = px;
    }
    __syncthreads();

    // ---- step 2: coalesced codebook-row reads, pixel-major into LDS
#pragma unroll
    for (int i = 0; i < 16; ++i) {
        const int p = w * 16 + i;
        const int k = sidx[p];                 // LDS read, wave-uniform -> broadcast
        zq[p][lane] = emb[k * 64 + lane];
    }
    __syncthreads();

    // ---- step 3: (B,D,H,W)-major float4 writes + fused loss
    const int p4 = (tid & 15) * 4;
    const float* zeb = z_e + batch * 262144 + hw0;
    float* ob = out + batch * 262144 + hw0;
    float ss = 0.f;
#pragma unroll
    for (int it = 0; it < 4; ++it) {
        const int d = (tid >> 4) + it * 16;
        float4 q;
        q.x = zq[p4 + 0][d]; q.y = zq[p4 + 1][d];
        q.z = zq[p4 + 2][d]; q.w = zq[p4 + 3][d];
        const float4 z = *(const float4*)(zeb + d * 4096 + p4);
        *(float4*)(ob + d * 4096 + p4) = q;
        const float e0 = q.x - z.x, e1 = q.y - z.y, e2 = q.z - z.z, e3 = q.w - z.w;
        ss += e0 * e0 + e1 * e1 + e2 * e2 + e3 * e3;
    }
    for (int off = 32; off; off >>= 1) ss += __shfl_down(ss, off, 64);
    if (lane == 0) sred[w] = ss;
    __syncthreads();
    if (tid == 0)
        atomicAdd(out + ZQ_ELEMS,
                  ((sred[0] + sred[1]) + (sred[2] + sred[3])) * (1.25f / (float)ZQ_ELEMS));
}

// Exact fp64 fixup: wave per flagged pixel; emb staged per 64-code tile into
// padded LDS. Patches idx + z_q row + loss delta. Grid 512; idle blocks exit.
__global__ __launch_bounds__(256) void vq_fix(const float* __restrict__ z_e,
        const float* __restrict__ emb, float* __restrict__ out,
        const int* __restrict__ cnt, const int* __restrict__ list) {
    const int n = *cnt;
    if ((int)blockIdx.x * 4 >= n) return;
    __shared__ float etile[64][65];
    const int tid  = threadIdx.x;
    const int lane = tid & 63;
    const int wv   = __builtin_amdgcn_readfirstlane(tid >> 6);

    for (int base = blockIdx.x * 4; base < n; base += gridDim.x * 4) {
        const int item = base + wv;
        const bool active = item < n;
        int pix = 0, oldk = 0;
        float f[64];
        if (active) {
            pix = list[item];
            const float* zb = z_e + (pix >> 12) * 262144 + (pix & 4095);
#pragma unroll
            for (int d = 0; d < 64; ++d) f[d] = zb[d * 4096];
            oldk = (int)out[ZQ_ELEMS + 1 + pix];
        }
        double best = INFINITY; int bk = KC;
        double dold = 0.0;
        for (int j = 0; j < 16; ++j) {
            __syncthreads();
#pragma unroll
            for (int i = 0; i < 16; ++i) {
                const int idx = i * 256 + tid;
                etile[idx >> 6][idx & 63] = emb[j * 4096 + idx];
            }
            __syncthreads();
            if (active) {
                const int k = j * 64 + lane;
                double a0 = 0.0, a1 = 0.0;
#pragma unroll
                for (int d = 0; d < 64; d += 2) {
                    const double d0 = (double)f[d]     - (double)etile[lane][d];
                    const double d1 = (double)f[d + 1] - (double)etile[lane][d + 1];
                    a0 = fma(d0, d0, a0);
                    a1 = fma(d1, d1, a1);
                }
                const double acc = a0 + a1;
                if (acc < best || (acc == best && k < bk)) { best = acc; bk = k; }
                if (k == oldk) dold = acc;
            }
        }
        if (active) {
            for (int off = 32; off; off >>= 1) {
                const double ov = __shfl_down(best, off, 64);
                const int    oi = __shfl_down(bk, off, 64);
                if (ov < best || (ov == best && oi < bk)) { best = ov; bk = oi; }
            }
            for (int off = 32; off; off >>= 1) dold += __shfl_down(dold, off, 64);
            bk   = __shfl(bk, 0, 64);
            best = __shfl(best, 0, 64);
            dold = __shfl(dold, 0, 64);
            if (bk != oldk) {
                if (lane == 0) out[ZQ_ELEMS + 1 + pix] = (float)bk;
                out[(pix >> 12) * 262144 + (pix & 4095) + lane * 4096] = emb[bk * 64 + lane];
                if (lane == 0)
                    atomicAdd(out + ZQ_ELEMS,
                              (float)((best - dold) * (1.25 / (double)ZQ_ELEMS)));
            }
        }
    }
}

extern "C" void kernel_launch(void* const* d_in, const int* in_sizes, int n_in,
                              void* d_out, int out_size, void* d_ws, size_t ws_size,
                              hipStream_t stream) {
    const float* z_e = (const float*)d_in[0];
    const float* emb = (const float*)d_in[1];
    float* out = (float*)d_out;
    char* ws = (char*)d_ws;
    unsigned short* epack = (unsigned short*)ws;
    float*  enorm     = (float*)(ws + 262144);
    int*    risky_cnt = (int*)(ws + 266240);
    int*    risky     = (int*)(ws + 270336);
    double* pbest     = (double*)(ws + 524288);     // 2 MB
    float*  pb2       = (float*)(ws + 2621440);     // 1 MB

    vq_prep<<<4, 256, 0, stream>>>(emb, epack, enorm, risky_cnt, out);
    vq_scan<<<2048, 256, 0, stream>>>(z_e, epack, enorm, pbest, pb2);
    vq_final<<<1024, 256, 0, stream>>>(z_e, emb, pbest, pb2, out, risky_cnt, risky);
    vq_fix<<<512, 256, 0, stream>>>(z_e, emb, out, risky_cnt, risky);
}

// Round 18
// 78.701 us; speedup vs baseline: 4.9949x; 1.1440x over previous
//
#include <hip/hip_runtime.h>
#include <math.h>

typedef short  short8 __attribute__((ext_vector_type(8)));
typedef float  f32x4  __attribute__((ext_vector_type(4)));

#define ZQ_ELEMS 4194304    // 16*64*64*64
#define KC       1024
#define EPS_HALF 0.005f

// Output layout (fp32, concat): [0,4194304) z_q_st ; [4194304] vq_loss ;
// [4194305, 4259841) indices (as float)
//
// ws layout (bytes):
//   [0,262144)           ushort epack[1024][128]   per code: hi[64] | lo[64]
//   [262144,266240)      float  enorm[1024]
//   [266240,266244)      int    risky_cnt
//   [270336,524288)      int    risky[63488]

__device__ inline unsigned short bf16_rne(float f) {
    union { float fv; unsigned u; } a; a.fv = f;
    unsigned r = a.u + 0x7FFFu + ((a.u >> 16) & 1u);
    return (unsigned short)(r >> 16);
}
__device__ inline float bf16_to_f(unsigned short h) {
    union { unsigned u; float fv; } a; a.u = ((unsigned)h) << 16;
    return a.fv;
}
// packed (score, 1023-code) ordered compare via f64 max; near-ties are all
// rescored exactly, so tie direction here is irrelevant.
__device__ inline double dpack(float hi, unsigned lo) {
    return __hiloint2double(__float_as_int(hi), (int)lo);
}
__device__ inline float dhi(double d) { return __int_as_float(__double2hiint(d)); }
__device__ inline unsigned dlo(double d) { return (unsigned)__double2loint(d); }

__global__ __launch_bounds__(256) void vq_prep(const float* __restrict__ emb,
        unsigned short* __restrict__ epack, float* __restrict__ enorm,
        int* __restrict__ risky_cnt, float* __restrict__ out) {
    const int k = blockIdx.x * 256 + threadIdx.x;   // grid 4
    if (k == 0) { *risky_cnt = 0; out[ZQ_ELEMS] = 0.f; }
    const float4* e4 = (const float4*)(emb + k * 64);
    float s = 0.f;
#pragma unroll
    for (int j = 0; j < 16; ++j) {
        float4 v = e4[j];
        float vv[4] = {v.x, v.y, v.z, v.w};
        ushort4 hv, lv;
        unsigned short h[4], l[4];
#pragma unroll
        for (int t = 0; t < 4; ++t) {
            s = fmaf(vv[t], vv[t], s);
            h[t] = bf16_rne(vv[t]);
            l[t] = bf16_rne(vv[t] - bf16_to_f(h[t]));
        }
        hv.x = h[0]; hv.y = h[1]; hv.z = h[2]; hv.w = h[3];
        lv.x = l[0]; lv.y = l[1]; lv.z = l[2]; lv.w = l[3];
        *(ushort4*)(epack + k * 128 + j * 4)      = hv;
        *(ushort4*)(epack + k * 128 + 64 + j * 4) = lv;
    }
    enorm[k] = s;
}

// Block-local full pipeline: block = 64 px x ALL 1024 codes (4 passes of the
// r10 wave geometry: 4 waves x 64 resident codes). Indices finalize in-block;
// gather + z_q write + loss run inline. Grid 1024. No cross-block dataflow.
__global__ __launch_bounds__(256) void vq_scan(const float* __restrict__ z_e,
        const unsigned short* __restrict__ epack, const float* __restrict__ enorm,
        const float* __restrict__ emb, float* __restrict__ out,
        int* __restrict__ risky_cnt, int* __restrict__ risky) {
    const int tid  = threadIdx.x;
    const int lane = tid & 63;
    const int col  = lane & 15;
    const int g    = lane >> 4;
    const int wv   = __builtin_amdgcn_readfirstlane(tid >> 6);
    const int pblk = blockIdx.x * 64;

    __shared__ __align__(16) char smem[19456];
    unsigned short* afrag = (unsigned short*)smem;          // [64 px][hi64|lo64]
    double* mrgB = (double*)(smem + 16384);                 // [4][64]
    float*  mrgS = (float*)(smem + 18432);                  // [4][64]
    float (*zq)[65] = (float (*)[65])smem;                  // gather alias (16.6KB)
    __shared__ int   sidx[64];
    __shared__ float sred[4];

    // ---- stage + convert 64 pixels into LDS (once; no redundancy)
    {
        const int lp = tid & 63;
        const int pg = pblk + lp;
        const float* zb = z_e + (pg >> 12) * 262144 + (pg & 4095);
        const int sx = (lp & 7) << 3;
#pragma unroll
        for (int s8 = 0; s8 < 2; ++s8) {
            const int d0 = wv * 16 + s8 * 8;
            short8 H, L;
#pragma unroll
            for (int j = 0; j < 8; ++j) {
                float v = zb[(d0 + j) * 4096];
                unsigned short h = bf16_rne(v);
                H[j] = (short)h;
                L[j] = (short)bf16_rne(v - bf16_to_f(h));
            }
            const int sw = d0 ^ sx;                // 16B-granular XOR swizzle
            *(short8*)&afrag[lp * 128 + sw]      = H;
            *(short8*)&afrag[lp * 128 + 64 + sw] = L;
        }
    }
    __syncthreads();

    const f32x4 zero4 = {0.f, 0.f, 0.f, 0.f};
    const int g8 = g * 8;

    double Brun[4];
    float  Srun[4];
#pragma unroll
    for (int it = 0; it < 4; ++it) { Brun[it] = dpack(-INFINITY, 0u); Srun[it] = -INFINITY; }

    // ---- 4 passes: wave's 64 resident codes sweep the 64 px (4 it x 16 px)
#pragma unroll 1
    for (int pass = 0; pass < 4; ++pass) {
        const int cbase = pass * 256 + wv * 64;
        short8 ah[4][2], al[4][2];
        f32x4 enf[4];
#pragma unroll
        for (int t = 0; t < 4; ++t) {
            const int code = cbase + t * 16 + col;
            const short8* ph = (const short8*)(epack + code * 128) + g;
            ah[t][0] = ph[0]; ah[t][1] = ph[4];
            al[t][0] = ph[8]; al[t][1] = ph[12];
            const float4 e4 = *(const float4*)(enorm + cbase + t * 16 + g * 4);
            enf[t][0] = -0.5f * e4.x; enf[t][1] = -0.5f * e4.y;
            enf[t][2] = -0.5f * e4.z; enf[t][3] = -0.5f * e4.w;
        }
        const int K1 = 1023 - cbase - g * 4;

#pragma unroll
        for (int it = 0; it < 4; ++it) {
            const int lpx = it * 16 + col;
            const int sxp = (lpx & 7) << 3;
            const unsigned short* ap = &afrag[lpx * 128];
            const short8 bh0 = *(const short8*)&ap[(g8     ) ^ sxp];
            const short8 bh1 = *(const short8*)&ap[(32 + g8) ^ sxp];
            const short8 bl0 = *(const short8*)&ap[64 + ((g8     ) ^ sxp)];
            const short8 bl1 = *(const short8*)&ap[64 + ((32 + g8) ^ sxp)];

            double B = Brun[it];
            float  S = Srun[it];
#pragma unroll
            for (int t = 0; t < 4; ++t) {
                f32x4 aA, aB;   // chunk0 / chunk1 independent 3-chains
                aA = __builtin_amdgcn_mfma_f32_16x16x32_bf16(ah[t][0], bh0, enf[t], 0, 0, 0);
                aB = __builtin_amdgcn_mfma_f32_16x16x32_bf16(ah[t][1], bh1, zero4, 0, 0, 0);
                aA = __builtin_amdgcn_mfma_f32_16x16x32_bf16(al[t][0], bh0, aA, 0, 0, 0);
                aB = __builtin_amdgcn_mfma_f32_16x16x32_bf16(al[t][1], bh1, aB, 0, 0, 0);
                aA = __builtin_amdgcn_mfma_f32_16x16x32_bf16(ah[t][0], bl0, aA, 0, 0, 0);
                aB = __builtin_amdgcn_mfma_f32_16x16x32_bf16(ah[t][1], bl1, aB, 0, 0, 0);
#pragma unroll
                for (int r = 0; r < 4; ++r) {
                    const float v = aA[r] + aB[r]; // score(code=cbase+t*16+g*4+r, px)
                    S = __builtin_amdgcn_fmed3f(dhi(B), S, v);
                    B = fmax(B, dpack(v, (unsigned)(K1 - t * 16 - r)));
                }
            }
            Brun[it] = B;
            Srun[it] = S;
        }
    }

    // ---- deferred reduce over g (lane bits 4-5): 4 independent shfl chains
#pragma unroll
    for (int it = 0; it < 4; ++it) {
        double B = Brun[it];
        float  S = Srun[it];
#pragma unroll
        for (int s = 16; s < 64; s <<= 1) {
            const double ob = __shfl_xor(B, s, 64);
            const float  o2 = __shfl_xor(S, s, 64);
            S = __builtin_amdgcn_fmed3f(dhi(B), dhi(ob), fmaxf(S, o2));
            B = fmax(B, ob);
        }
        Brun[it] = B;
        Srun[it] = S;
    }
    __syncthreads();              // afrag reads complete
    if (g == 0) {
#pragma unroll
        for (int it = 0; it < 4; ++it) {
            mrgB[wv * 64 + it * 16 + col] = Brun[it];
            mrgS[wv * 64 + it * 16 + col] = Srun[it];
        }
    }
    __syncthreads();

    // ---- wave 0: merge the 4 waves' results -> idx + risky compact
    if (tid < 64) {
        double B = mrgB[tid];
        float  S = mrgS[tid];
#pragma unroll
        for (int w = 1; w < 4; ++w) {
            const double ob = mrgB[w * 64 + tid];
            const float  o2 = mrgS[w * 64 + tid];
            S = __builtin_amdgcn_fmed3f(dhi(B), dhi(ob), fmaxf(S, o2));
            B = fmax(B, ob);
        }
        const int idx = 1023 - (int)dlo(B);
        sidx[tid] = idx;
        out[ZQ_ELEMS + 1 + pblk + tid] = (float)idx;
        const bool risk = (dhi(B) - S < EPS_HALF);
        const unsigned long long m = __ballot(risk);
        int base = 0;
        if (lane == 0 && m) base = atomicAdd(risky_cnt, __popcll(m));
        base = __shfl(base, 0, 64);
        if (risk) risky[base + __popcll(m & ((1ull << lane) - 1ull))] = pblk + tid;
    }
    __syncthreads();

    // ---- gather: coalesced codebook-row reads (zq aliases afrag+mrgB)
#pragma unroll
    for (int i = 0; i < 16; ++i) {
        const int p = wv * 16 + i;
        const int k = sidx[p];                 // LDS read, wave-uniform broadcast
        zq[p][lane] = emb[k * 64 + lane];
    }
    __syncthreads();

    // ---- (B,D,H,W)-major float4 writes + fused loss
    const int batch = pblk >> 12;
    const int hw0   = pblk & 4095;
    const int p4 = (tid & 15) * 4;
    const float* zeb = z_e + batch * 262144 + hw0;
    float* ob = out + batch * 262144 + hw0;
    float ss = 0.f;
#pragma unroll
    for (int it = 0; it < 4; ++it) {
        const int d = (tid >> 4) + it * 16;
        float4 q;
        q.x = zq[p4 + 0][d]; q.y = zq[p4 + 1][d];
        q.z = zq[p4 + 2][d]; q.w = zq[p4 + 3][d];
        const float4 z = *(const float4*)(zeb + d * 4096 + p4);
        *(float4*)(ob + d * 4096 + p4) = q;
        const float e0 = q.x - z.x, e1 = q.y - z.y, e2 = q.z - z.z, e3 = q.w - z.w;
        ss += e0 * e0 + e1 * e1 + e2 * e2 + e3 * e3;
    }
    for (int off = 32; off; off >>= 1) ss += __shfl_down(ss, off, 64);
    if (lane == 0) sred[wv] = ss;
    __syncthreads();
    if (tid == 0)
        atomicAdd(out + ZQ_ELEMS,
                  ((sred[0] + sred[1]) + (sred[2] + sred[3])) * (1.25f / (float)ZQ_ELEMS));
}

// Exact fp64 fixup: wave per flagged pixel; emb staged per 64-code tile into
// padded LDS. Patches idx + z_q row + loss delta. Grid 512; idle blocks exit.
__global__ __launch_bounds__(256) void vq_fix(const float* __restrict__ z_e,
        const float* __restrict__ emb, float* __restrict__ out,
        const int* __restrict__ cnt, const int* __restrict__ list) {
    const int n = *cnt;
    if ((int)blockIdx.x * 4 >= n) return;
    __shared__ float etile[64][65];
    const int tid  = threadIdx.x;
    const int lane = tid & 63;
    const int wv   = __builtin_amdgcn_readfirstlane(tid >> 6);

    for (int base = blockIdx.x * 4; base < n; base += gridDim.x * 4) {
        const int item = base + wv;
        const bool active = item < n;
        int pix = 0, oldk = 0;
        float f[64];
        if (active) {
            pix = list[item];
            const float* zb = z_e + (pix >> 12) * 262144 + (pix & 4095);
#pragma unroll
            for (int d = 0; d < 64; ++d) f[d] = zb[d * 4096];
            oldk = (int)out[ZQ_ELEMS + 1 + pix];
        }
        double best = INFINITY; int bk = KC;
        double dold = 0.0;
        for (int j = 0; j < 16; ++j) {
            __syncthreads();
#pragma unroll
            for (int i = 0; i < 16; ++i) {
                const int idx = i * 256 + tid;
                etile[idx >> 6][idx & 63] = emb[j * 4096 + idx];
            }
            __syncthreads();
            if (active) {
                const int k = j * 64 + lane;
                double a0 = 0.0, a1 = 0.0;
#pragma unroll
                for (int d = 0; d < 64; d += 2) {
                    const double d0 = (double)f[d]     - (double)etile[lane][d];
                    const double d1 = (double)f[d + 1] - (double)etile[lane][d + 1];
                    a0 = fma(d0, d0, a0);
                    a1 = fma(d1, d1, a1);
                }
                const double acc = a0 + a1;
                if (acc < best || (acc == best && k < bk)) { best = acc; bk = k; }
                if (k == oldk) dold = acc;
            }
        }
        if (active) {
            for (int off = 32; off; off >>= 1) {
                const double ov = __shfl_down(best, off, 64);
                const int    oi = __shfl_down(bk, off, 64);
                if (ov < best || (ov == best && oi < bk)) { best = ov; bk = oi; }
            }
            for (int off = 32; off; off >>= 1) dold += __shfl_down(dold, off, 64);
            bk   = __shfl(bk, 0, 64);
            best = __shfl(best, 0, 64);
            dold = __shfl(dold, 0, 64);
            if (bk != oldk) {
                if (lane == 0) out[ZQ_ELEMS + 1 + pix] = (float)bk;
                out[(pix >> 12) * 262144 + (pix & 4095) + lane * 4096] = emb[bk * 64 + lane];
                if (lane == 0)
                    atomicAdd(out + ZQ_ELEMS,
                              (float)((best - dold) * (1.25 / (double)ZQ_ELEMS)));
            }
        }
    }
}

extern "C" void kernel_launch(void* const* d_in, const int* in_sizes, int n_in,
                              void* d_out, int out_size, void* d_ws, size_t ws_size,
                              hipStream_t stream) {
    const float* z_e = (const float*)d_in[0];
    const float* emb = (const float*)d_in[1];
    float* out = (float*)d_out;
    char* ws = (char*)d_ws;
    unsigned short* epack = (unsigned short*)ws;
    float*  enorm     = (float*)(ws + 262144);
    int*    risky_cnt = (int*)(ws + 266240);
    int*    risky     = (int*)(ws + 270336);

    vq_prep<<<4, 256, 0, stream>>>(emb, epack, enorm, risky_cnt, out);
    vq_scan<<<1024, 256, 0, stream>>>(z_e, epack, enorm, emb, out, risky_cnt, risky);
    vq_fix<<<512, 256, 0, stream>>>(z_e, emb, out, risky_cnt, risky);
}